// Round 3
// baseline (752.563 us; speedup 1.0000x reference)
//
#include <hip/hip_runtime.h>
#include <cstdint>
#include <cstddef>

typedef unsigned short u16;
typedef __attribute__((ext_vector_type(8))) short short8;
typedef __attribute__((ext_vector_type(4))) float f32x4;

// ---------- constants (match reference) ----------
#define HC_ 128
// dot-table row offsets (rows of 4 floats)
#define OFF_U0   0
#define OFF_I0   202
#define OFF_T0   404
#define OFF_UD0  606
#define OFF_ID0  1107
#define OFF_U2   1608
#define OFF_I2   2410
#define OFF_T2   3212
#define OFF_UD2  4014
#define OFF_ID2  4515
#define DOT_ROWS 5016

__device__ __forceinline__ float b2f(u16 u) {
  union { unsigned int i; float f; } v; v.i = ((unsigned int)u) << 16; return v.f;
}
__device__ __forceinline__ u16 f2b(float f) {
  union { float f; unsigned int i; } v; v.f = f;
  unsigned int r = v.i + 0x7fffu + ((v.i >> 16) & 1u);
  return (u16)(r >> 16);
}

// ---------- generic MFMA GEMM: C[M,N] = epi(A[M,K] @ W[K,N]) ----------
// A: bf16 (AF32=0) or fp32 (AF32=1). W,bias: fp32. Out: bf16 (OF32=0) or fp32.
// EPI: 0=none 2=lrelu(x+bias) 3=x+bias ; RELUA: relu A on load
template<int EPI, int RELUA, int KS, int AF32, int OF32>
__global__ __launch_bounds__(256) void gemm_k(
    const void* __restrict__ A_, const float* __restrict__ W,
    const float* __restrict__ bias, void* __restrict__ C_, int M, int N)
{
  const int lane = threadIdx.x & 63;
  const int wave = threadIdx.x >> 6;
  const int quad = lane >> 4;
  const int l16  = lane & 15;
  const int n0   = blockIdx.y * 64 + wave * 16;
  if (n0 >= N) return;

  short8 bfrag[KS];
#pragma unroll
  for (int ks = 0; ks < KS; ++ks) {
    short8 bf;
    const int kb = ks * 32 + quad * 8;
#pragma unroll
    for (int j = 0; j < 8; ++j)
      bf[j] = (short)f2b(W[(size_t)(kb + j) * N + n0 + l16]);
    bfrag[ks] = bf;
  }
  float bv = 0.f;
  if (EPI == 2 || EPI == 3) bv = bias[n0 + l16];

  const int mtiles = M >> 4;
  for (int mt = blockIdx.x; mt < mtiles; mt += gridDim.x) {
    f32x4 acc = {0.f, 0.f, 0.f, 0.f};
    if (AF32) {
      const float* arow = (const float*)A_ + (size_t)(mt * 16 + l16) * (KS * 32);
#pragma unroll
      for (int ks = 0; ks < KS; ++ks) {
        short8 af;
#pragma unroll
        for (int j = 0; j < 8; ++j) {
          float v = arow[ks * 32 + quad * 8 + j];
          if (RELUA) v = fmaxf(v, 0.f);
          af[j] = (short)f2b(v);
        }
        acc = __builtin_amdgcn_mfma_f32_16x16x32_bf16(af, bfrag[ks], acc, 0, 0, 0);
      }
    } else {
      const u16* arow = (const u16*)A_ + (size_t)(mt * 16 + l16) * (KS * 32);
#pragma unroll
      for (int ks = 0; ks < KS; ++ks) {
        short8 af = *(const short8*)(arow + ks * 32 + quad * 8);
        if (RELUA) {
#pragma unroll
          for (int j = 0; j < 8; ++j) af[j] = (af[j] < (short)0) ? (short)0 : af[j];
        }
        acc = __builtin_amdgcn_mfma_f32_16x16x32_bf16(af, bfrag[ks], acc, 0, 0, 0);
      }
    }
#pragma unroll
    for (int r = 0; r < 4; ++r) {
      float v = acc[r];
      if (EPI == 2)      { v += bv; v = (v > 0.f) ? v : 0.2f * v; }
      else if (EPI == 3) { v += bv; }
      const size_t idx = (size_t)(mt * 16 + quad * 4 + r) * N + n0 + l16;
      if (OF32) ((float*)C_)[idx] = v;
      else      ((u16*)C_)[idx] = f2b(v);
    }
  }
}

// ---------- fused rnn GEMM: out = tanh( cvt(A1 fp32)@W1 + [relu]A2@W2 ), N=128 ----------
// W1,W2 bf16 (internal); A2 bf16; out bf16. GATHER: rows indexed by gidx.
template<int RELU2, int GATHER>
__global__ __launch_bounds__(256) void gemm2_k(
    const float* __restrict__ A1, const u16* __restrict__ W1,
    const u16* __restrict__ A2, const u16* __restrict__ W2,
    const int* __restrict__ gidx, u16* __restrict__ Cout, int M)
{
  const int lane = threadIdx.x & 63;
  const int wave = threadIdx.x >> 6;
  const int quad = lane >> 4;
  const int l16  = lane & 15;
  const int n0   = blockIdx.y * 64 + wave * 16;   // N fixed 128, grid.y==2

  short8 bf1[4], bf2[4];
#pragma unroll
  for (int ks = 0; ks < 4; ++ks) {
    short8 a, b;
    const int kb = ks * 32 + quad * 8;
#pragma unroll
    for (int j = 0; j < 8; ++j) {
      a[j] = (short)W1[(size_t)(kb + j) * HC_ + n0 + l16];
      b[j] = (short)W2[(size_t)(kb + j) * HC_ + n0 + l16];
    }
    bf1[ks] = a; bf2[ks] = b;
  }

  const int mtiles = M >> 4;
  for (int mt = blockIdx.x; mt < mtiles; mt += gridDim.x) {
    const int rowm = mt * 16 + l16;
    const int g = GATHER ? gidx[rowm] : rowm;
    const float* a1 = A1 + (size_t)g * HC_;
    const u16*   a2 = A2 + (size_t)g * HC_;
    f32x4 acc = {0.f, 0.f, 0.f, 0.f};
#pragma unroll
    for (int ks = 0; ks < 4; ++ks) {
      short8 af;
      const float* p = a1 + ks * 32 + quad * 8;
#pragma unroll
      for (int j = 0; j < 8; ++j) af[j] = (short)f2b(p[j]);
      acc = __builtin_amdgcn_mfma_f32_16x16x32_bf16(af, bf1[ks], acc, 0, 0, 0);
    }
#pragma unroll
    for (int ks = 0; ks < 4; ++ks) {
      short8 af = *(const short8*)(a2 + ks * 32 + quad * 8);
      if (RELU2) {
#pragma unroll
        for (int j = 0; j < 8; ++j) af[j] = (af[j] < (short)0) ? (short)0 : af[j];
      }
      acc = __builtin_amdgcn_mfma_f32_16x16x32_bf16(af, bf2[ks], acc, 0, 0, 0);
    }
#pragma unroll
    for (int r = 0; r < 4; ++r)
      Cout[(size_t)(mt * 16 + quad * 4 + r) * HC_ + n0 + l16] = f2b(tanhf(acc[r]));
  }
}

// ---------- x = bf16(id_emb[node_idx]) ----------
__global__ void gather_x_k(const int* __restrict__ nidx, const float* __restrict__ emb,
                           u16* __restrict__ x, int Nn)
{
  int t = blockIdx.x * blockDim.x + threadIdx.x;
  int n = t >> 4, c = (t & 15) << 3;
  if (n >= Nn) return;
  int id = nidx[n];
  const float* s = emb + (size_t)id * HC_ + c;
  u16 tmp[8];
#pragma unroll
  for (int j = 0; j < 8; ++j) tmp[j] = f2b(s[j]);
  *(short8*)(x + (size_t)n * HC_ + c) = *(short8*)tmp;
}

// ---------- fp32 -> bf16 copy ----------
__global__ void cvt_k(const float* __restrict__ in, u16* __restrict__ out, int n)
{
  int t = blockIdx.x * blockDim.x + threadIdx.x;
  if (t < n) out[t] = f2b(in[t]);
}

// ---------- center mask scatter ----------
__global__ void mask_k(const int* __restrict__ center, int* __restrict__ mask, int B_)
{
  int t = blockIdx.x * blockDim.x + threadIdx.x;
  if (t < B_) mask[center[t]] = 1;
}

// ---------- att-bias dot tables (all fp32 inputs) ----------
__global__ void dots_k(const float* u0, const float* i0, const float* t0,
                       const float* ud0, const float* id0,
                       const float* u2, const float* i2, const float* t2,
                       const float* ud2, const float* id2,
                       const float* asrc0, const float* asrc1, float* __restrict__ out)
{
  int t = blockIdx.x * blockDim.x + threadIdx.x;
  if (t >= DOT_ROWS * 4) return;
  int r = t >> 2, h = t & 3;
  const float* tab; int lr; const float* as;
  if      (r < OFF_I0)  { tab = u0;  lr = r;            as = asrc0; }
  else if (r < OFF_T0)  { tab = i0;  lr = r - OFF_I0;   as = asrc0; }
  else if (r < OFF_UD0) { tab = t0;  lr = r - OFF_T0;   as = asrc0; }
  else if (r < OFF_ID0) { tab = ud0; lr = r - OFF_UD0;  as = asrc0; }
  else if (r < OFF_U2)  { tab = id0; lr = r - OFF_ID0;  as = asrc0; }
  else if (r < OFF_I2)  { tab = u2;  lr = r - OFF_U2;   as = asrc1; }
  else if (r < OFF_T2)  { tab = i2;  lr = r - OFF_I2;   as = asrc1; }
  else if (r < OFF_UD2) { tab = t2;  lr = r - OFF_T2;   as = asrc1; }
  else if (r < OFF_ID2) { tab = ud2; lr = r - OFF_UD2;  as = asrc1; }
  else                  { tab = id2; lr = r - OFF_ID2;  as = asrc1; }
  float s = 0.f;
#pragma unroll
  for (int c = 0; c < 32; ++c)
    s += tab[(size_t)lr * HC_ + h * 32 + c] * as[h * 32 + c];
  out[t] = s;
}

// ---------- wq[layer][k][h] = sum_c wr[k][h*32+c] * adst[h*32+c] ----------
__global__ void wq_k(const float* __restrict__ wr0, const float* __restrict__ adst0,
                     const float* __restrict__ wr1, const float* __restrict__ adst1,
                     float* __restrict__ wq)
{
  int t = blockIdx.x * blockDim.x + threadIdx.x;
  if (t >= 1024) return;
  int layer = t >> 9, k = (t >> 2) & 127, h = t & 3;
  const float* wr = layer ? wr1 : wr0;
  const float* ad = layer ? adst1 : adst0;
  float s = 0.f;
#pragma unroll
  for (int c = 0; c < 32; ++c)
    s += wr[(size_t)k * HC_ + h * 32 + c] * ad[h * 32 + c];
  wq[t] = s;
}

// ---------- kdot[n,h] = k[n]·asrc[h] ; qdot[n,h] = ([relu]hrow) @ wq[:,h] ----------
template<int RELU>
__global__ void kq_k(const u16* __restrict__ kbuf, const u16* __restrict__ hbuf,
                     const float* __restrict__ asrc, const float* __restrict__ wq,
                     float* __restrict__ kdot, float* __restrict__ qdot, int Nn)
{
  int t = blockIdx.x * blockDim.x + threadIdx.x;
  int n = t >> 2, h = t & 3;
  if (n >= Nn) return;
  float s1 = 0.f;
#pragma unroll
  for (int c = 0; c < 32; ++c)
    s1 += b2f(kbuf[(size_t)n * HC_ + h * 32 + c]) * asrc[h * 32 + c];
  float s2 = 0.f;
#pragma unroll
  for (int kk = 0; kk < HC_; ++kk) {
    u16 v = hbuf[(size_t)n * HC_ + kk];
    if (RELU && (v & 0x8000u)) v = 0;
    s2 += b2f(v) * wq[kk * 4 + h];
  }
  kdot[n * 4 + h] = s1;
  qdot[n * 4 + h] = s2;
}

// ---------- edge pass A: a = exp(leaky(logit)); den[dst] += a ----------
__global__ void passA_k(const int* __restrict__ src, const int* __restrict__ dst,
                        const int* __restrict__ ety, const int* __restrict__ toff,
                        const int* __restrict__ dist,
                        const float* __restrict__ kdot, const float* __restrict__ qdot,
                        const float* __restrict__ dots,
                        int off_u, int off_i, int off_t, int off_ud, int off_id,
                        float* __restrict__ abuf, float* __restrict__ den,
                        const int* __restrict__ mask, int Ecnt)
{
  int t = blockIdx.x * blockDim.x + threadIdx.x;
  int e = t >> 2, h = t & 3;
  if (e >= Ecnt) return;
  int d = dst[e];
  if (mask && mask[d] == 0) return;
  int ty = ety[e];
  int to = toff[e];
  int arow = (ty == 0) ? (off_u + to) : (ty < 2) ? (off_i + to) : (off_t + to);
  float l = kdot[src[e] * 4 + h] + qdot[d * 4 + h] + dots[arow * 4 + h];
  if (ty == 0 || ty == 2 || ty == 3) {
    int drow = ((ty == 0) ? off_ud : off_id) + dist[e];
    l += dots[drow * 4 + h];
  }
  l = (l > 0.f) ? l : 0.2f * l;
  float a = __expf(fminf(l, 30.f));
  abuf[e * 4 + h] = a;
  atomicAdd(&den[d * 4 + h], a);
}

// ---------- edge pass C: CO[dst,ch] += alpha * (k[src,ch] + eb + ed) ----------
__global__ __launch_bounds__(256) void passC_k(
    const int* __restrict__ src, const int* __restrict__ dst,
    const int* __restrict__ ety, const int* __restrict__ toff,
    const int* __restrict__ dist,
    const u16* __restrict__ kbuf,
    const float* __restrict__ uemb, const float* __restrict__ iemb, const float* __restrict__ temb,
    const float* __restrict__ udemb, const float* __restrict__ idemb,
    const float* __restrict__ abuf, const float* __restrict__ den,
    float* __restrict__ CO, const int* __restrict__ mask, int Ecnt)
{
  int t = blockIdx.x * 256 + threadIdx.x;
  int e = t >> 7;
  if (e >= Ecnt) return;
  int ch = t & 127, h = ch >> 5;
  int d = dst[e];
  if (mask && mask[d] == 0) return;
  float alpha = abuf[e * 4 + h] / fmaxf(den[d * 4 + h], 1e-16f);
  int ty = ety[e], to = toff[e];
  float m = b2f(kbuf[(size_t)src[e] * HC_ + ch]);
  const float* et = (ty == 0) ? uemb : (ty < 2) ? iemb : temb;
  m += et[(size_t)to * HC_ + ch];
  if (ty == 0 || ty == 2 || ty == 3) {
    const float* dt = (ty == 0) ? udemb : idemb;
    m += dt[(size_t)dist[e] * HC_ + ch];
  }
  atomicAdd(&CO[(size_t)d * HC_ + ch], alpha * m);
}

// ---------- feat[b] = [x[nid] | h1[nid] | h2c[b]] (all bf16 internal) ----------
__global__ void packfeat_k(const u16* __restrict__ x, const u16* __restrict__ h1,
                           const u16* __restrict__ h2c, const int* __restrict__ center,
                           u16* __restrict__ feat, int B_)
{
  int t = blockIdx.x * blockDim.x + threadIdx.x;
  int b = t / 48, cc = t % 48;
  if (b >= B_) return;
  int c0 = cc << 3;
  int nid = center[b];
  const u16* s;
  if (c0 < 128)      s = x   + (size_t)nid * HC_ + c0;
  else if (c0 < 256) s = h1  + (size_t)nid * HC_ + (c0 - 128);
  else               s = h2c + (size_t)b   * HC_ + (c0 - 256);
  *(short8*)(feat + (size_t)b * 384 + c0) = *(const short8*)s;
}

// =======================================================================
extern "C" void kernel_launch(void* const* d_in, const int* in_sizes, int n_in,
                              void* d_out, int out_size, void* d_ws, size_t ws_size,
                              hipStream_t stream)
{
  (void)n_in; (void)out_size; (void)ws_size;
  const int* node_idx = (const int*)d_in[0];
  const int* eidx     = (const int*)d_in[1];
  const int* etype    = (const int*)d_in[2];
  const int* toff0    = (const int*)d_in[3];
  const int* toff1    = (const int*)d_in[4];
  const int* dist0    = (const int*)d_in[5];
  const int* dist1    = (const int*)d_in[6];
  const int* center   = (const int*)d_in[7];
  const float* id_emb   = (const float*)d_in[8];
  const float* u_att    = (const float*)d_in[9];
  const float* i_att    = (const float*)d_in[10];
  const float* t_att    = (const float*)d_in[11];
  const float* u_emb    = (const float*)d_in[12];
  const float* i_emb    = (const float*)d_in[13];
  const float* t_emb    = (const float*)d_in[14];
  const float* u_att2   = (const float*)d_in[15];
  const float* i_att2   = (const float*)d_in[16];
  const float* t_att2   = (const float*)d_in[17];
  const float* u_emb2   = (const float*)d_in[18];
  const float* i_emb2   = (const float*)d_in[19];
  const float* t_emb2   = (const float*)d_in[20];
  const float* ud_att   = (const float*)d_in[21];
  const float* id_att   = (const float*)d_in[22];
  const float* ud_emb   = (const float*)d_in[23];
  const float* id_embd  = (const float*)d_in[24];
  const float* ud_att2  = (const float*)d_in[25];
  const float* id_att2  = (const float*)d_in[26];
  const float* ud_emb2  = (const float*)d_in[27];
  const float* id_emb2  = (const float*)d_in[28];
  const float* trans_head = (const float*)d_in[29];
  const float* rnn_w    = (const float*)d_in[30];
  const float* w1       = (const float*)d_in[31];
  const float* b1       = (const float*)d_in[32];
  const float* w2       = (const float*)d_in[33];
  const float* b2       = (const float*)d_in[34];
  const float* wl0      = (const float*)d_in[35];
  const float* wr0      = (const float*)d_in[36];
  const float* asrc0    = (const float*)d_in[37];
  const float* adst0    = (const float*)d_in[38];
  const float* wl1      = (const float*)d_in[39];
  const float* wr1      = (const float*)d_in[40];
  const float* asrc1    = (const float*)d_in[41];
  const float* adst1    = (const float*)d_in[42];

  const int N_    = in_sizes[0];
  const int E_    = in_sizes[2];
  const int B_    = in_sizes[7];
  const int ITEM_ = in_sizes[34];
  const int* esrc = eidx;
  const int* edst = eidx + E_;

  // ---- workspace carve-up (256B aligned), ~71 MB ----
  char* ws = (char*)d_ws;
  size_t off = 0;
  auto alloc = [&](size_t bytes) -> char* {
    char* p = ws + off;
    off += (bytes + 255) & ~(size_t)255;
    return p;
  };
  float* CO_b  = (float*)alloc((size_t)N_ * HC_ * 4);   // 25.6M
  u16*   k_b   = (u16*)  alloc((size_t)N_ * HC_ * 2);   // 12.8M
  u16*   x_b   = (u16*)  alloc((size_t)N_ * HC_ * 2);   // 12.8M
  u16*   h1_b  = (u16*)  alloc((size_t)N_ * HC_ * 2);   // 12.8M
  float* abuf  = (float*)alloc((size_t)E_ * 4 * 4);     // 3.2M
  float* kdot  = (float*)alloc((size_t)N_ * 4 * 4);
  float* qdot  = (float*)alloc((size_t)N_ * 4 * 4);
  float* den   = (float*)alloc((size_t)N_ * 4 * 4);
  float* dots  = (float*)alloc((size_t)DOT_ROWS * 4 * 4);
  int*   mask  = (int*)  alloc((size_t)N_ * 4);
  float* wq    = (float*)alloc(1024 * 4);               // wq0 | wq1
  u16*   rnn_wb= (u16*)  alloc(256 * HC_ * 2);          // bf16 copy of rnn_w
  u16*   Wt    = (u16*)  alloc(HC_ * HC_ * 2);          // bf16(trans_head @ rnn_w_bot)
  u16*   h2c   = (u16*)  alloc((size_t)B_ * HC_ * 2);
  u16*   feat  = (u16*)  alloc((size_t)B_ * 384 * 2);
  u16*   hdd   = (u16*)  alloc((size_t)B_ * HC_ * 2);

  const int TB = 256;
  auto nb = [&](long long t) { return (int)((t + TB - 1) / TB); };

  // 0) mask + small precomputes
  hipMemsetAsync(mask, 0, (size_t)N_ * 4, stream);
  mask_k<<<nb(B_), TB, 0, stream>>>(center, mask, B_);
  gather_x_k<<<nb((long long)N_ * 16), TB, 0, stream>>>(node_idx, id_emb, x_b, N_);
  dots_k<<<nb(DOT_ROWS * 4), TB, 0, stream>>>(u_att, i_att, t_att, ud_att, id_att,
                                              u_att2, i_att2, t_att2, ud_att2, id_att2,
                                              asrc0, asrc1, dots);
  wq_k<<<4, TB, 0, stream>>>(wr0, adst0, wr1, adst1, wq);
  cvt_k<<<nb(256 * HC_), TB, 0, stream>>>(rnn_w, rnn_wb, 256 * HC_);
  // Wt = bf16(trans_head @ rnn_w[128:,:])
  gemm_k<0,0,4,1,0><<<dim3(8, 2), TB, 0, stream>>>(trans_head, rnn_w + HC_ * HC_,
                                                   nullptr, Wt, HC_, HC_);

  // 1) layer 0: k0 = x @ wl0 ; kdot/qdot
  gemm_k<0,0,4,0,0><<<dim3(640, 2), TB, 0, stream>>>(x_b, wl0, nullptr, k_b, N_, HC_);
  kq_k<0><<<nb((long long)N_ * 4), TB, 0, stream>>>(k_b, x_b, asrc0, wq, kdot, qdot, N_);

  // 2) layer-0 attention
  hipMemsetAsync(den, 0, (size_t)N_ * 16, stream);
  passA_k<<<nb((long long)E_ * 4), TB, 0, stream>>>(esrc, edst, etype, toff0, dist0,
      kdot, qdot, dots, OFF_U0, OFF_I0, OFF_T0, OFF_UD0, OFF_ID0, abuf, den, nullptr, E_);
  hipMemsetAsync(CO_b, 0, (size_t)N_ * HC_ * 4, stream);
  passC_k<<<nb((long long)E_ * HC_), TB, 0, stream>>>(esrc, edst, etype, toff0, dist0,
      k_b, u_emb, i_emb, t_emb, ud_emb, id_embd, abuf, den, CO_b, nullptr, E_);

  // 3) h1 = tanh(CO @ rnn_w_top + x @ Wt)
  gemm2_k<0,0><<<dim3(640, 2), TB, 0, stream>>>(CO_b, rnn_wb, x_b, Wt, nullptr, h1_b, N_);

  // 4) layer 1: k1 = relu(h1) @ wl1 ; kdot/qdot
  gemm_k<0,1,4,0,0><<<dim3(640, 2), TB, 0, stream>>>(h1_b, wl1, nullptr, k_b, N_, HC_);
  kq_k<1><<<nb((long long)N_ * 4), TB, 0, stream>>>(k_b, h1_b, asrc1, wq + 512, kdot, qdot, N_);

  // 5) layer-1 attention (masked to center dsts)
  hipMemsetAsync(den, 0, (size_t)N_ * 16, stream);
  passA_k<<<nb((long long)E_ * 4), TB, 0, stream>>>(esrc, edst, etype, toff1, dist1,
      kdot, qdot, dots, OFF_U2, OFF_I2, OFF_T2, OFF_UD2, OFF_ID2, abuf, den, mask, E_);
  hipMemsetAsync(CO_b, 0, (size_t)N_ * HC_ * 4, stream);
  passC_k<<<nb((long long)E_ * HC_), TB, 0, stream>>>(esrc, edst, etype, toff1, dist1,
      k_b, u_emb2, i_emb2, t_emb2, ud_emb2, id_emb2, abuf, den, CO_b, mask, E_);

  // 6) h2 (center rows only) = tanh(CO[nid] @ rnn_w_top + relu(h1[nid]) @ rnn_w_bot)
  gemm2_k<1,1><<<dim3(64, 2), TB, 0, stream>>>(CO_b, rnn_wb, h1_b, rnn_wb + HC_ * HC_,
                                               center, h2c, B_);

  // 7) feat = [x | h1 | h2][center]; hdd = lrelu(feat @ w1 + b1)
  packfeat_k<<<nb((long long)B_ * 48), TB, 0, stream>>>(x_b, h1_b, h2c, center, feat, B_);
  gemm_k<2,0,12,0,0><<<dim3(64, 2), TB, 0, stream>>>(feat, w1, b1, hdd, B_, HC_);

  // 8) logits = hdd @ w2 + b2  -> d_out (fp32)
  gemm_k<3,0,4,0,1><<<dim3(8, (ITEM_ + 63) / 64), TB, 0, stream>>>(hdd, w2, b2, d_out, B_, ITEM_);
}